// Round 9
// baseline (249.396 us; speedup 1.0000x reference)
//
#include <hip/hip_runtime.h>
#include <hip/hip_bf16.h>
#include <stdint.h>

#define B_ 4
#define N_ 4096
#define D_ 256
#define K_ 64
#define BN_ (B_*N_)

typedef __attribute__((ext_vector_type(8))) short bf16x8;
typedef __attribute__((ext_vector_type(8))) unsigned short u16x8;
typedef __attribute__((ext_vector_type(4))) float f32x4;
typedef __attribute__((address_space(1))) const unsigned int gas_u32;
typedef __attribute__((address_space(3))) unsigned int las_u32;

static __device__ __forceinline__ unsigned short f2bf(float f) {
  union { float f; unsigned u; } x; x.f = f;
  unsigned r = x.u + 0x7fffu + ((x.u >> 16) & 1u);
  return (unsigned short)(r >> 16);
}
static __device__ __forceinline__ float bf2f(unsigned short u) {
  union { unsigned u; float f; } x; x.u = ((unsigned)u) << 16;
  return x.f;
}
static __device__ __forceinline__ f32x4 mfma16(bf16x8 a, bf16x8 b, f32x4 c) {
  return __builtin_amdgcn_mfma_f32_16x16x32_bf16(a, b, c, 0, 0, 0);
}

// ---------------- kernel 1: normalize rows + W->bf16 + vsum zero ----------------
__global__ __launch_bounds__(256) void prep_kernel(
    const float* __restrict__ x, const float* __restrict__ W,
    unsigned short* __restrict__ xn, float* __restrict__ norms,
    unsigned short* __restrict__ Wb, float* __restrict__ vsum) {
  const int bid = blockIdx.x;
  if (bid < 4096) {
    int row = bid * 4 + (threadIdx.x >> 6);
    int lane = threadIdx.x & 63;
    const float4 v = reinterpret_cast<const float4*>(x + (size_t)row * D_)[lane];
    float ss = v.x*v.x + v.y*v.y + v.z*v.z + v.w*v.w;
    #pragma unroll
    for (int off = 32; off > 0; off >>= 1) ss += __shfl_xor(ss, off);
    float nrm = sqrtf(ss);
    float scale = 1.0f / fmaxf(nrm, 1e-12f);
    ushort4 o;
    o.x = f2bf(v.x * scale); o.y = f2bf(v.y * scale);
    o.z = f2bf(v.z * scale); o.w = f2bf(v.w * scale);
    reinterpret_cast<ushort4*>(xn + (size_t)row * D_)[lane] = o;
    if (lane == 0) norms[row] = nrm;
  } else if (bid < 4160) {
    int i = (bid - 4096) * 256 + threadIdx.x;
    float4 v = reinterpret_cast<const float4*>(W)[i];
    ushort4 o; o.x = f2bf(v.x); o.y = f2bf(v.y); o.z = f2bf(v.z); o.w = f2bf(v.w);
    reinterpret_cast<ushort4*>(Wb)[i] = o;
  } else {
    reinterpret_cast<float4*>(vsum)[threadIdx.x] = (float4){0.f, 0.f, 0.f, 0.f};
  }
}

// ---------------- kernel 2: unified 128x128-tile GEMM, pipelined + XCD swizzle ----
// XCD-aware tile mapping: 4352 % 8 == 0 -> each XCD gets 544 CONSECUTIVE tiles,
// so its L2 holds one batch's B-panels (2 MB < 4 MB) instead of thrashing on
// all of xn (8 MB). Per K-step: ds_read frags -> barrier -> stage next -> MFMA.
__global__ __launch_bounds__(256, 3) void compute_kernel(
    const unsigned short* __restrict__ xn, const float* __restrict__ norms,
    const unsigned short* __restrict__ Wb, const float* __restrict__ bias,
    unsigned short* __restrict__ value, float* __restrict__ vsum,
    unsigned short* __restrict__ S) {
  __shared__ __attribute__((aligned(16))) unsigned char smem[33792];
  unsigned char* As = smem;                 // 16 KB swizzled A tile [128][64]
  unsigned char* Bs = smem + 16384;         // 16 KB swizzled B tile [128][64]
  float* ns_s   = (float*)(smem + 32768);   // [128] (value mode)
  float* bias_s = (float*)(smem + 33280);   // [128] (value mode)

  const int t = threadIdx.x, lane = t & 63, w = t >> 6;
  const int l15 = lane & 15, qv = lane >> 4, rb = qv * 4;
  const int wr = w >> 1, wc = w & 1;
  const int x7 = l15 & 7;

  // bijective XCD swizzle (nwg=4352=8*544)
  const int bidx = (blockIdx.x & 7) * 544 + (blockIdx.x >> 3);

  const unsigned short* Asrc;
  const unsigned short* Bsrc;
  int rbG, cb, batch = 0;
  const bool vmode = (bidx < 256);
  if (vmode) {
    rbG = (bidx >> 1) * 128;
    cb  = (bidx & 1) * 128;
    Asrc = xn + (size_t)rbG * D_;
    Bsrc = Wb + (size_t)cb * D_;
    if (t < 128) { ns_s[t] = norms[rbG + t]; bias_s[t] = bias[cb + t]; }
  } else {
    int g = bidx - 256;
    batch = g >> 10;
    int tl = g & 1023;
    rbG = (tl >> 5) * 128;
    cb  = (tl & 31) * 128;
    Asrc = xn + ((size_t)batch * N_ + rbG) * D_;
    Bsrc = xn + ((size_t)batch * N_ + cb)  * D_;
  }

  auto STAGE = [&](int kk) {
    #pragma unroll
    for (int p = 0; p < 4; p++) {
      int q = t + p * 256;                  // 0..1023
      int row = q >> 3, c = q & 7;
      int cg = (c ^ (row & 7)) * 8;         // pre-swizzled source chunk (elems)
      __builtin_amdgcn_global_load_lds(
          (gas_u32*)(Asrc + (size_t)row * D_ + kk * 64 + cg),
          (las_u32*)(As + q * 16), 16, 0, 0);
      __builtin_amdgcn_global_load_lds(
          (gas_u32*)(Bsrc + (size_t)row * D_ + kk * 64 + cg),
          (las_u32*)(Bs + q * 16), 16, 0, 0);
    }
  };

  f32x4 acc[4][4];
  #pragma unroll
  for (int i = 0; i < 4; i++)
    #pragma unroll
    for (int j = 0; j < 4; j++) acc[i][j] = (f32x4){0.f,0.f,0.f,0.f};

  STAGE(0);
  __syncthreads();
  for (int kk = 0; kk < 4; kk++) {
    bf16x8 afr[2][4], bfr[2][4];
    #pragma unroll
    for (int ks = 0; ks < 2; ks++) {
      const int cpos = (((ks * 4 + qv) ^ x7) << 4);
      #pragma unroll
      for (int rt = 0; rt < 4; rt++)
        afr[ks][rt] = *(const bf16x8*)(As + (wr*64 + rt*16 + l15) * 128 + cpos);
      #pragma unroll
      for (int ct = 0; ct < 4; ct++)
        bfr[ks][ct] = *(const bf16x8*)(Bs + (wc*64 + ct*16 + l15) * 128 + cpos);
    }
    __syncthreads();                        // all waves' frag reads retired
    if (kk < 3) STAGE(kk + 1);              // overwrite tile; MFMA hides flight
    #pragma unroll
    for (int ks = 0; ks < 2; ks++)
      #pragma unroll
      for (int rt = 0; rt < 4; rt++)
        #pragma unroll
        for (int ct = 0; ct < 4; ct++)
          acc[rt][ct] = mfma16(afr[ks][rt], bfr[ks][ct], acc[rt][ct]);
    if (kk < 3) __syncthreads();            // drains vmcnt(0): stage landed
  }

  // ---- epilogue via swizzled LDS bounce over As/Bs region ----
  unsigned short* kbuf = (unsigned short*)smem;   // [128][128] u16 = 32 KB
  if (vmode) {
    float vpart[4] = {0.f, 0.f, 0.f, 0.f};
    #pragma unroll
    for (int rt = 0; rt < 4; rt++)
      #pragma unroll
      for (int ct = 0; ct < 4; ct++) {
        int col_l = wc*64 + ct*16 + l15;
        #pragma unroll
        for (int reg = 0; reg < 4; reg++) {
          int row_l = wr*64 + rt*16 + rb + reg;
          float v = acc[rt][ct][reg] * ns_s[row_l] + bias_s[col_l];
          int pos = (col_l & 7) | ((((col_l >> 3) ^ (row_l & 7))) << 3);
          kbuf[row_l * 128 + pos] = f2bf(v);
          vpart[ct] += v;
        }
      }
    int b2 = rbG >> 12;
    #pragma unroll
    for (int ct = 0; ct < 4; ct++)
      atomicAdd(&vsum[b2*D_ + cb + wc*64 + ct*16 + l15], vpart[ct]);
    __syncthreads();
    #pragma unroll
    for (int p = 0; p < 8; p++) {
      int q = t + p * 256;
      int row = q >> 4, c8 = q & 15;
      u16x8 d = *(const u16x8*)(kbuf + row * 128 + ((c8 ^ (row & 7)) << 3));
      *(u16x8*)(value + (size_t)(rbG + row) * D_ + cb + c8 * 8) = d;
    }
  } else {
    #pragma unroll
    for (int rt = 0; rt < 4; rt++)
      #pragma unroll
      for (int ct = 0; ct < 4; ct++) {
        int col_l = wc*64 + ct*16 + l15;
        #pragma unroll
        for (int reg = 0; reg < 4; reg++) {
          int row_l = wr*64 + rt*16 + rb + reg;
          unsigned short bits = f2bf(acc[rt][ct][reg]);
          unsigned short key = (bits & 0x8000u) ? (unsigned short)(~bits)
                                                : (unsigned short)(bits | 0x8000u);
          int pos = (col_l & 7) | ((((col_l >> 3) ^ (row_l & 7))) << 3);
          kbuf[row_l * 128 + pos] = key;
        }
      }
    __syncthreads();
    unsigned short* Sb = S + ((size_t)batch << 24);
    #pragma unroll
    for (int p = 0; p < 8; p++) {
      int q = t + p * 256;
      int row = q >> 4, c8 = q & 15;
      u16x8 d = *(const u16x8*)(kbuf + row * 128 + ((c8 ^ (row & 7)) << 3));
      *(u16x8*)(Sb + (size_t)(rbG + row) * N_ + cb + c8 * 8) = d;
    }
  }
}

// ---------------- kernel 3: wave-per-row top-64 + sparse softmax @ V ----------
// Zero barriers; ballot/ffs boundary picks; mask-driven take loop (keys
// re-read from L1-resident srow to avoid dynamic register indexing).
__global__ __launch_bounds__(256) void select_kernel(
    const unsigned short* __restrict__ S,
    const unsigned short* __restrict__ value,
    const float* __restrict__ vsum,
    float* __restrict__ out) {
  __shared__ unsigned hist[4][1024];      // 16 KB: per-wave packed bins
  __shared__ unsigned pair2[4][64][2];    //  2 KB: (byte-offset, weight bits)
  __shared__ int cnts[4][2];              // nsel, neq per wave

  const int t = threadIdx.x, lane = t & 63, w = t >> 6;
  const int rowg = blockIdx.x * 4 + w;
  const int b = rowg >> 12;
  const int r = rowg & 4095;
  const unsigned short* srow = S + ((size_t)b << 24) + ((size_t)r << 12);

  // load the row's 4096 keys: 64 keys/lane as 8 x 16B (coalesced)
  uint4 kq[8];
  #pragma unroll
  for (int c = 0; c < 8; c++)
    kq[c] = *(const uint4*)(srow + c*512 + lane*8);

  #pragma unroll
  for (int p = 0; p < 4; p++)
    *(uint4*)&hist[w][lane*16 + p*4] = (uint4){0u,0u,0u,0u};
  if (lane == 0) { cnts[w][0] = 0; cnts[w][1] = 0; }

  // pass 1: 2048-bin histogram (bin = key>>5), u16-packed pairs
  #pragma unroll
  for (int c = 0; c < 8; c++) {
    unsigned uu[4] = {kq[c].x, kq[c].y, kq[c].z, kq[c].w};
    #pragma unroll
    for (int m = 0; m < 4; m++) {
      unsigned u = uu[m];
      atomicAdd(&hist[w][(u & 0xffffu) >> 6], 1u << (((u >> 5) & 1u) * 16));
      atomicAdd(&hist[w][u >> 22],            1u << (((u >> 21) & 1u) * 16));
    }
  }

  // lane owns words [lane*16, lane*16+16) = bins [lane*32, lane*32+32)
  unsigned hw[16];
  #pragma unroll
  for (int p = 0; p < 4; p++)
    *(uint4*)&hw[p*4] = *(const uint4*)&hist[w][lane*16 + p*4];
  unsigned ltot = 0;
  #pragma unroll
  for (int i = 0; i < 16; i++) ltot += (hw[i] & 0xffffu) + (hw[i] >> 16);

  // wave suffix-scan over lane totals; boundary lane via ballot
  unsigned v = ltot;
  #pragma unroll
  for (int off = 1; off < 64; off <<= 1) {
    unsigned o = __shfl_down(v, off);
    if (lane + off < 64) v += o;
  }
  unsigned above = v - ltot;
  unsigned long long m1 = __ballot(v >= 64u && above < 64u);
  int bl = (int)(__ffsll(m1) - 1);
  unsigned above_bl = __shfl(above, bl);

  // lane j<32 handles bin bl*32+j: read boundary lane's words from LDS
  unsigned wbc = hist[w][bl*16 + ((lane & 31) >> 1)];
  unsigned cj = (lane & 1) ? (wbc >> 16) : (wbc & 0xffffu);
  unsigned sv = cj;
  #pragma unroll
  for (int off = 1; off < 32; off <<= 1) {
    unsigned o = __shfl_down(sv, off);
    if (lane + off < 32) sv += o;
  }
  unsigned sj = sv + above_bl;
  unsigned abj = sj - cj;
  unsigned long long m2 = __ballot(lane < 32 && sj >= 64u && abj < 64u);
  int jb = (int)(__ffsll(m2) - 1);
  const unsigned hb = ((unsigned)bl << 5) | (unsigned)jb;
  const unsigned cg = __shfl(abj, jb);
  const unsigned cjc = __shfl(cj, jb);
  const unsigned need2 = 64u - cg;                          // >= 1 guaranteed

  unsigned tau; int needeq;
  if (need2 == cjc && hb > 0u) {
    // whole boundary bin taken: threshold just below the bin
    tau = (hb << 5) - 1u; needeq = 0;
  } else {
    // pass 2: 32 bins over low-5 bits within bin hb (16 packed words)
    if (lane < 16) hist[w][lane] = 0;
    #pragma unroll
    for (int c = 0; c < 8; c++) {
      unsigned uu[4] = {kq[c].x, kq[c].y, kq[c].z, kq[c].w};
      #pragma unroll
      for (int m = 0; m < 4; m++) {
        unsigned klo = uu[m] & 0xffffu, khi = uu[m] >> 16;
        if ((klo >> 5) == hb) atomicAdd(&hist[w][(klo & 31u) >> 1], 1u << ((klo & 1u) * 16));
        if ((khi >> 5) == hb) atomicAdd(&hist[w][(khi & 31u) >> 1], 1u << ((khi & 1u) * 16));
      }
    }
    unsigned wv2 = hist[w][(lane & 31) >> 1];
    unsigned c2 = (lane & 1) ? (wv2 >> 16) : (wv2 & 0xffffu);
    unsigned s2 = c2;
    #pragma unroll
    for (int off = 1; off < 32; off <<= 1) {
      unsigned o = __shfl_down(s2, off);
      if (lane + off < 32) s2 += o;
    }
    unsigned ab2 = s2 - c2;
    unsigned long long m3 = __ballot(lane < 32 && s2 >= need2 && ab2 < need2);
    int lb = (int)(__ffsll(m3) - 1);
    unsigned cg2 = __shfl(ab2, lb);
    tau = (hb << 5) | (unsigned)lb;
    needeq = (int)(need2 - cg2);                            // >= 1 guaranteed
  }

  // take via 64-bit masks; ~1 selected/lane -> short ffs loops
  float zloc = 0.f;
  unsigned long long gtm = 0ull, eqm = 0ull;
  #pragma unroll
  for (int c = 0; c < 8; c++) {
    unsigned uu[4] = {kq[c].x, kq[c].y, kq[c].z, kq[c].w};
    #pragma unroll
    for (int m = 0; m < 4; m++) {
      unsigned klo = uu[m] & 0xffffu, khi = uu[m] >> 16;
      int base = c*8 + m*2;
      gtm |= ((unsigned long long)(klo > tau)) << base;
      gtm |= ((unsigned long long)(khi > tau)) << (base + 1);
      eqm |= ((unsigned long long)(klo == tau)) << base;
      eqm |= ((unsigned long long)(khi == tau)) << (base + 1);
    }
  }
  while (gtm) {
    int i = (int)(__ffsll(gtm) - 1); gtm &= gtm - 1ull;
    int col = (i >> 3) * 512 + lane * 8 + (i & 7);
    unsigned key = srow[col];                               // L1/L2 hit
    unsigned short bits = (key & 0x8000u) ? (unsigned short)(key & 0x7fffu)
                                          : (unsigned short)(~key);
    float e = __expf(bf2f(bits));
    zloc += e;
    int slot = atomicAdd(&cnts[w][0], 1);
    pair2[w][slot][0] = (unsigned)col << 9;                 // idx * 512 bytes
    pair2[w][slot][1] = __float_as_uint(e - 1.0f);
  }
  if (needeq > 0 && eqm) {
    unsigned short bitsq = (tau & 0x8000u) ? (unsigned short)(tau & 0x7fffu)
                                           : (unsigned short)(~tau);
    float etau = __expf(bf2f(bitsq));
    float em1 = etau - 1.0f;
    while (eqm) {
      int i = (int)(__ffsll(eqm) - 1); eqm &= eqm - 1ull;
      int k = atomicAdd(&cnts[w][1], 1);
      if (k >= needeq) break;                               // later tickets also fail
      int col = (i >> 3) * 512 + lane * 8 + (i & 7);
      zloc += etau;
      int slot = atomicAdd(&cnts[w][0], 1);
      pair2[w][slot][0] = (unsigned)col << 9;
      pair2[w][slot][1] = __float_as_uint(em1);
    }
  }
  #pragma unroll
  for (int off = 32; off > 0; off >>= 1) zloc += __shfl_xor(zloc, off);
  const float invZ = 1.0f / (zloc + (float)(N_ - K_));

  // gather: 64 value rows (bf16), lane covers cols [lane*4, lane*4+4)
  const char* vbb = (const char*)value + ((size_t)b << 21);
  float a0 = 0.f, a1 = 0.f, a2 = 0.f, a3 = 0.f;
  for (int i = 0; i < 64; i++) {
    uint2 pr = *(const uint2*)&pair2[w][i][0];     // broadcast ds_read_b64
    float wt = __uint_as_float(pr.y);
    uint2 vv = *(const uint2*)(vbb + pr.x + lane*8);
    a0 += wt * __uint_as_float(vv.x << 16);
    a1 += wt * __uint_as_float(vv.x & 0xffff0000u);
    a2 += wt * __uint_as_float(vv.y << 16);
    a3 += wt * __uint_as_float(vv.y & 0xffff0000u);
  }
  float4 vs = *(const float4*)(vsum + b*D_ + lane*4);
  float4 o;
  o.x = (a0 + vs.x) * invZ; o.y = (a1 + vs.y) * invZ;
  o.z = (a2 + vs.z) * invZ; o.w = (a3 + vs.w) * invZ;
  *(float4*)(out + (size_t)rowg * D_ + lane*4) = o;
}

extern "C" void kernel_launch(void* const* d_in, const int* in_sizes, int n_in,
                              void* d_out, int out_size, void* d_ws, size_t ws_size,
                              hipStream_t stream) {
  const float* x    = (const float*)d_in[0];
  const float* W    = (const float*)d_in[1];
  const float* bias = (const float*)d_in[2];
  float* out = (float*)d_out;
  char* ws = (char*)d_ws;
  unsigned short* xn    = (unsigned short*)(ws);              //  8 MB  bf16 normed x
  unsigned short* Wb    = (unsigned short*)(ws + 8388608);    // 128 KB bf16 W
  float*          norms = (float*)(ws + 8519680);             //  64 KB
  unsigned short* value = (unsigned short*)(ws + 8585216);    //  8 MB  bf16 value
  float*          vsum  = (float*)(ws + 16973824);            //   4 KB
  unsigned short* S     = (unsigned short*)(ws + 16977920);   // 4 x 32 MB ordered-u16 S

  prep_kernel<<<4161, 256, 0, stream>>>(x, W, xn, norms, Wb, vsum);
  compute_kernel<<<4352, 256, 0, stream>>>(xn, norms, Wb, bias, value, vsum, S);
  select_kernel<<<BN_/4, 256, 0, stream>>>(S, value, vsum, out);
}

// Round 10
// 241.777 us; speedup vs baseline: 1.0315x; 1.0315x over previous
//
#include <hip/hip_runtime.h>
#include <hip/hip_bf16.h>
#include <stdint.h>

#define B_ 4
#define N_ 4096
#define D_ 256
#define K_ 64
#define BN_ (B_*N_)

typedef __attribute__((ext_vector_type(8))) short bf16x8;
typedef __attribute__((ext_vector_type(8))) unsigned short u16x8;
typedef __attribute__((ext_vector_type(4))) float f32x4;
typedef __attribute__((address_space(1))) const unsigned int gas_u32;
typedef __attribute__((address_space(3))) unsigned int las_u32;

static __device__ __forceinline__ unsigned short f2bf(float f) {
  union { float f; unsigned u; } x; x.f = f;
  unsigned r = x.u + 0x7fffu + ((x.u >> 16) & 1u);
  return (unsigned short)(r >> 16);
}
static __device__ __forceinline__ float bf2f(unsigned short u) {
  union { unsigned u; float f; } x; x.u = ((unsigned)u) << 16;
  return x.f;
}
static __device__ __forceinline__ f32x4 mfma16(bf16x8 a, bf16x8 b, f32x4 c) {
  return __builtin_amdgcn_mfma_f32_16x16x32_bf16(a, b, c, 0, 0, 0);
}

// ---------------- kernel 1: normalize rows + W->bf16 + vsum zero ----------------
__global__ __launch_bounds__(256) void prep_kernel(
    const float* __restrict__ x, const float* __restrict__ W,
    unsigned short* __restrict__ xn, float* __restrict__ norms,
    unsigned short* __restrict__ Wb, float* __restrict__ vsum) {
  const int bid = blockIdx.x;
  if (bid < 4096) {
    int row = bid * 4 + (threadIdx.x >> 6);
    int lane = threadIdx.x & 63;
    const float4 v = reinterpret_cast<const float4*>(x + (size_t)row * D_)[lane];
    float ss = v.x*v.x + v.y*v.y + v.z*v.z + v.w*v.w;
    #pragma unroll
    for (int off = 32; off > 0; off >>= 1) ss += __shfl_xor(ss, off);
    float nrm = sqrtf(ss);
    float scale = 1.0f / fmaxf(nrm, 1e-12f);
    ushort4 o;
    o.x = f2bf(v.x * scale); o.y = f2bf(v.y * scale);
    o.z = f2bf(v.z * scale); o.w = f2bf(v.w * scale);
    reinterpret_cast<ushort4*>(xn + (size_t)row * D_)[lane] = o;
    if (lane == 0) norms[row] = nrm;
  } else if (bid < 4160) {
    int i = (bid - 4096) * 256 + threadIdx.x;
    float4 v = reinterpret_cast<const float4*>(W)[i];
    ushort4 o; o.x = f2bf(v.x); o.y = f2bf(v.y); o.z = f2bf(v.z); o.w = f2bf(v.w);
    reinterpret_cast<ushort4*>(Wb)[i] = o;
  } else {
    reinterpret_cast<float4*>(vsum)[threadIdx.x] = (float4){0.f, 0.f, 0.f, 0.f};
  }
}

// ---------------- kernel 2: unified 128x128-tile GEMM, pipelined ----------------
// No XCD swizzle (L3-resident data: swizzle measured -10% in r9). LDS exactly
// 32 KB -> 5 blocks/CU by LDS; launch_bounds(256,4) guarantees 4.
// Per K-step: ds_read frags -> barrier -> stage next -> MFMA -> barrier.
__global__ __launch_bounds__(256, 4) void compute_kernel(
    const unsigned short* __restrict__ xn, const float* __restrict__ norms,
    const unsigned short* __restrict__ Wb, const float* __restrict__ bias,
    unsigned short* __restrict__ value, float* __restrict__ vsum,
    unsigned short* __restrict__ S) {
  __shared__ __attribute__((aligned(16))) unsigned char smem[32768];
  unsigned char* As = smem;                 // 16 KB swizzled A tile [128][64]
  unsigned char* Bs = smem + 16384;         // 16 KB swizzled B tile [128][64]

  const int t = threadIdx.x, lane = t & 63, w = t >> 6;
  const int l15 = lane & 15, qv = lane >> 4, rb = qv * 4;
  const int wr = w >> 1, wc = w & 1;
  const int x7 = l15 & 7;

  const int bidx = blockIdx.x;

  const unsigned short* Asrc;
  const unsigned short* Bsrc;
  int rbG, cb, batch = 0;
  const bool vmode = (bidx < 256);
  if (vmode) {
    rbG = (bidx >> 1) * 128;
    cb  = (bidx & 1) * 128;
    Asrc = xn + (size_t)rbG * D_;
    Bsrc = Wb + (size_t)cb * D_;
  } else {
    int g = bidx - 256;
    batch = g >> 10;
    int tl = g & 1023;
    rbG = (tl >> 5) * 128;
    cb  = (tl & 31) * 128;
    Asrc = xn + ((size_t)batch * N_ + rbG) * D_;
    Bsrc = xn + ((size_t)batch * N_ + cb)  * D_;
  }

  auto STAGE = [&](int kk) {
    #pragma unroll
    for (int p = 0; p < 4; p++) {
      int q = t + p * 256;                  // 0..1023
      int row = q >> 3, c = q & 7;
      int cg = (c ^ (row & 7)) * 8;         // pre-swizzled source chunk (elems)
      __builtin_amdgcn_global_load_lds(
          (gas_u32*)(Asrc + (size_t)row * D_ + kk * 64 + cg),
          (las_u32*)(As + q * 16), 16, 0, 0);
      __builtin_amdgcn_global_load_lds(
          (gas_u32*)(Bsrc + (size_t)row * D_ + kk * 64 + cg),
          (las_u32*)(Bs + q * 16), 16, 0, 0);
    }
  };

  f32x4 acc[4][4];
  #pragma unroll
  for (int i = 0; i < 4; i++)
    #pragma unroll
    for (int j = 0; j < 4; j++) acc[i][j] = (f32x4){0.f,0.f,0.f,0.f};

  STAGE(0);
  __syncthreads();
  for (int kk = 0; kk < 4; kk++) {
    bf16x8 afr[2][4], bfr[2][4];
    #pragma unroll
    for (int ks = 0; ks < 2; ks++) {
      const int cpos = (((ks * 4 + qv) ^ x7) << 4);
      #pragma unroll
      for (int rt = 0; rt < 4; rt++)
        afr[ks][rt] = *(const bf16x8*)(As + (wr*64 + rt*16 + l15) * 128 + cpos);
      #pragma unroll
      for (int ct = 0; ct < 4; ct++)
        bfr[ks][ct] = *(const bf16x8*)(Bs + (wc*64 + ct*16 + l15) * 128 + cpos);
    }
    __syncthreads();                        // all waves' frag reads retired
    if (kk < 3) STAGE(kk + 1);              // overwrite tile; MFMA hides flight
    #pragma unroll
    for (int ks = 0; ks < 2; ks++)
      #pragma unroll
      for (int rt = 0; rt < 4; rt++)
        #pragma unroll
        for (int ct = 0; ct < 4; ct++)
          acc[rt][ct] = mfma16(afr[ks][rt], bfr[ks][ct], acc[rt][ct]);
    if (kk < 3) __syncthreads();            // drains vmcnt(0): stage landed
  }

  // ---- epilogue via swizzled LDS bounce over As/Bs region ----
  unsigned short* kbuf = (unsigned short*)smem;   // [128][128] u16 = 32 KB
  if (vmode) {
    // norms/bias read straight from global (tiny, L2-hot; only 256 blocks)
    float nsv[4][4], bsv[4];
    #pragma unroll
    for (int rt = 0; rt < 4; rt++)
      #pragma unroll
      for (int reg = 0; reg < 4; reg++)
        nsv[rt][reg] = norms[rbG + wr*64 + rt*16 + rb + reg];
    #pragma unroll
    for (int ct = 0; ct < 4; ct++)
      bsv[ct] = bias[cb + wc*64 + ct*16 + l15];
    float vpart[4] = {0.f, 0.f, 0.f, 0.f};
    #pragma unroll
    for (int rt = 0; rt < 4; rt++)
      #pragma unroll
      for (int ct = 0; ct < 4; ct++) {
        int col_l = wc*64 + ct*16 + l15;
        #pragma unroll
        for (int reg = 0; reg < 4; reg++) {
          int row_l = wr*64 + rt*16 + rb + reg;
          float v = acc[rt][ct][reg] * nsv[rt][reg] + bsv[ct];
          int pos = (col_l & 7) | ((((col_l >> 3) ^ (row_l & 7))) << 3);
          kbuf[row_l * 128 + pos] = f2bf(v);
          vpart[ct] += v;
        }
      }
    int b2 = rbG >> 12;
    #pragma unroll
    for (int ct = 0; ct < 4; ct++)
      atomicAdd(&vsum[b2*D_ + cb + wc*64 + ct*16 + l15], vpart[ct]);
    __syncthreads();
    #pragma unroll
    for (int p = 0; p < 8; p++) {
      int q = t + p * 256;
      int row = q >> 4, c8 = q & 15;
      u16x8 d = *(const u16x8*)(kbuf + row * 128 + ((c8 ^ (row & 7)) << 3));
      *(u16x8*)(value + (size_t)(rbG + row) * D_ + cb + c8 * 8) = d;
    }
  } else {
    #pragma unroll
    for (int rt = 0; rt < 4; rt++)
      #pragma unroll
      for (int ct = 0; ct < 4; ct++) {
        int col_l = wc*64 + ct*16 + l15;
        #pragma unroll
        for (int reg = 0; reg < 4; reg++) {
          int row_l = wr*64 + rt*16 + rb + reg;
          unsigned short bits = f2bf(acc[rt][ct][reg]);
          unsigned short key = (bits & 0x8000u) ? (unsigned short)(~bits)
                                                : (unsigned short)(bits | 0x8000u);
          int pos = (col_l & 7) | ((((col_l >> 3) ^ (row_l & 7))) << 3);
          kbuf[row_l * 128 + pos] = key;
        }
      }
    __syncthreads();
    unsigned short* Sb = S + ((size_t)batch << 24);
    #pragma unroll
    for (int p = 0; p < 8; p++) {
      int q = t + p * 256;
      int row = q >> 4, c8 = q & 15;
      u16x8 d = *(const u16x8*)(kbuf + row * 128 + ((c8 ^ (row & 7)) << 3));
      *(u16x8*)(Sb + (size_t)(rbG + row) * N_ + cb + c8 * 8) = d;
    }
  }
}

// ---------------- kernel 3: wave-per-row top-64 + sparse softmax @ V ----------
// Round-8 proven structure; histogram now HALF-WAVE-private (2 copies/wave,
// 8 total) to halve hot-bin same-address atomic serialization. Zero barriers.
__global__ __launch_bounds__(256) void select_kernel(
    const unsigned short* __restrict__ S,
    const unsigned short* __restrict__ value,
    const float* __restrict__ vsum,
    float* __restrict__ out) {
  __shared__ unsigned hist2[8][1024];     // 32 KB: per-half-wave packed bins
  __shared__ unsigned pair2[4][64][2];    //  2 KB: (byte-offset, weight bits)
  __shared__ int cnts[4][2];              // nsel, neq per wave

  const int t = threadIdx.x, lane = t & 63, w = t >> 6;
  const int cpi = w*2 + (lane >> 5);      // this lane's histogram copy
  const int rowg = blockIdx.x * 4 + w;
  const int b = rowg >> 12;
  const int r = rowg & 4095;
  const unsigned short* srow = S + ((size_t)b << 24) + ((size_t)r << 12);

  // load the row's 4096 keys: 64 keys/lane as 8 x 16B (coalesced)
  uint4 kq[8];
  #pragma unroll
  for (int c = 0; c < 8; c++)
    kq[c] = *(const uint4*)(srow + c*512 + lane*8);

  // zero this wave's 2 copies (2048 words, wave-local)
  {
    unsigned* hb0 = &hist2[w*2][0];
    #pragma unroll
    for (int p = 0; p < 8; p++)
      *(uint4*)&hb0[lane*32 + p*4] = (uint4){0u,0u,0u,0u};
  }
  if (lane == 0) { cnts[w][0] = 0; cnts[w][1] = 0; }

  // pass 1: 2048-bin histogram (bin = key>>5), u16-packed pairs
  #pragma unroll
  for (int c = 0; c < 8; c++) {
    unsigned uu[4] = {kq[c].x, kq[c].y, kq[c].z, kq[c].w};
    #pragma unroll
    for (int m = 0; m < 4; m++) {
      unsigned u = uu[m];
      atomicAdd(&hist2[cpi][(u & 0xffffu) >> 6], 1u << (((u >> 5) & 1u) * 16));
      atomicAdd(&hist2[cpi][u >> 22],            1u << (((u >> 21) & 1u) * 16));
    }
  }

  // lane owns words [lane*16, lane*16+16) = bins [lane*32, lane*32+32); merge 2 copies
  unsigned hw[16];
  #pragma unroll
  for (int p = 0; p < 4; p++) {
    uint4 A0 = *(const uint4*)&hist2[w*2][lane*16 + p*4];
    uint4 A1 = *(const uint4*)&hist2[w*2+1][lane*16 + p*4];
    hw[p*4+0] = A0.x + A1.x; hw[p*4+1] = A0.y + A1.y;
    hw[p*4+2] = A0.z + A1.z; hw[p*4+3] = A0.w + A1.w;
  }
  unsigned ltot = 0;
  #pragma unroll
  for (int i = 0; i < 16; i++) ltot += (hw[i] & 0xffffu) + (hw[i] >> 16);

  // wave suffix-scan over lane totals (bins ascend with lane; top = lane 63)
  unsigned v = ltot;
  #pragma unroll
  for (int off = 1; off < 64; off <<= 1) {
    unsigned o = __shfl_down(v, off);
    if (lane + off < 64) v += o;
  }
  unsigned above = v - ltot;
  int pk = -1;
  if (v >= 64u && above < 64u) {
    unsigned c = above; int hbl = 0; unsigned cgl = 0;
    #pragma unroll
    for (int j = 31; j >= 0; j--) {
      unsigned cj = (j & 1) ? (hw[j >> 1] >> 16) : (hw[j >> 1] & 0xffffu);
      unsigned cn = c + cj;
      if (cn >= 64u && c < 64u) { hbl = lane*32 + j; cgl = c; }
      c = cn;
    }
    pk = (hbl << 6) | (int)cgl;
  }
  #pragma unroll
  for (int off = 1; off < 64; off <<= 1) pk = max(pk, __shfl_xor(pk, off));
  const unsigned hb = (unsigned)(pk >> 6);
  const unsigned need2 = 64u - (unsigned)(pk & 63);        // >= 1 guaranteed

  // pass 2: 32 bins over low-5 bits within bin hb (16 packed words x 2 copies)
  if (lane < 32) hist2[w*2 + (lane >> 4)][lane & 15] = 0;
  #pragma unroll
  for (int c = 0; c < 8; c++) {
    unsigned uu[4] = {kq[c].x, kq[c].y, kq[c].z, kq[c].w};
    #pragma unroll
    for (int m = 0; m < 4; m++) {
      unsigned klo = uu[m] & 0xffffu, khi = uu[m] >> 16;
      if ((klo >> 5) == hb) atomicAdd(&hist2[cpi][(klo & 31u) >> 1], 1u << ((klo & 1u) * 16));
      if ((khi >> 5) == hb) atomicAdd(&hist2[cpi][(khi & 31u) >> 1], 1u << ((khi & 1u) * 16));
    }
  }
  unsigned wv2 = hist2[w*2][(lane & 31) >> 1] + hist2[w*2+1][(lane & 31) >> 1];
  unsigned c2 = (lane & 1) ? (wv2 >> 16) : (wv2 & 0xffffu);
  unsigned s2 = c2;
  #pragma unroll
  for (int off = 1; off < 32; off <<= 1) {
    unsigned o = __shfl_down(s2, off);
    if (lane + off < 32) s2 += o;
  }
  unsigned ab2 = s2 - c2;
  int pk2 = -1;
  if (lane < 32 && s2 >= need2 && ab2 < need2) pk2 = (lane << 6) | (int)ab2;
  #pragma unroll
  for (int off = 1; off < 64; off <<= 1) pk2 = max(pk2, __shfl_xor(pk2, off));
  const unsigned tau = (hb << 5) | (unsigned)(pk2 >> 6);
  const int needeq = (int)need2 - (pk2 & 63);              // >= 1 guaranteed

  // take: exactly 64 selected (ties by ticket); store (byte-off, e-1)
  float zloc = 0.f;
  #pragma unroll
  for (int c = 0; c < 8; c++) {
    int cb0 = c*512 + lane*8;
    unsigned uu[4] = {kq[c].x, kq[c].y, kq[c].z, kq[c].w};
    #pragma unroll
    for (int m = 0; m < 4; m++) {
      #pragma unroll
      for (int h = 0; h < 2; h++) {
        unsigned key = h ? (uu[m] >> 16) : (uu[m] & 0xffffu);
        bool take = key > tau;
        if (!take && key == tau) { int k = atomicAdd(&cnts[w][1], 1); take = (k < needeq); }
        if (take) {
          int slot = atomicAdd(&cnts[w][0], 1);
          unsigned short bits = (key & 0x8000u) ? (unsigned short)(key & 0x7fffu)
                                                : (unsigned short)(~key);
          float e = __expf(bf2f(bits));
          zloc += e;
          pair2[w][slot][0] = (unsigned)(cb0 + m*2 + h) << 9;   // idx * 512 bytes
          pair2[w][slot][1] = __float_as_uint(e - 1.0f);
        }
      }
    }
  }
  #pragma unroll
  for (int off = 32; off > 0; off >>= 1) zloc += __shfl_xor(zloc, off);
  const float invZ = 1.0f / (zloc + (float)(N_ - K_));

  // gather: 64 value rows (bf16), lane covers cols [lane*4, lane*4+4)
  const char* vbb = (const char*)value + ((size_t)b << 21);
  float a0 = 0.f, a1 = 0.f, a2 = 0.f, a3 = 0.f;
  for (int i = 0; i < 64; i++) {
    uint2 pr = *(const uint2*)&pair2[w][i][0];     // broadcast ds_read_b64
    float wt = __uint_as_float(pr.y);
    uint2 vv = *(const uint2*)(vbb + pr.x + lane*8);
    a0 += wt * __uint_as_float(vv.x << 16);
    a1 += wt * __uint_as_float(vv.x & 0xffff0000u);
    a2 += wt * __uint_as_float(vv.y << 16);
    a3 += wt * __uint_as_float(vv.y & 0xffff0000u);
  }
  float4 vs = *(const float4*)(vsum + b*D_ + lane*4);
  float4 o;
  o.x = (a0 + vs.x) * invZ; o.y = (a1 + vs.y) * invZ;
  o.z = (a2 + vs.z) * invZ; o.w = (a3 + vs.w) * invZ;
  *(float4*)(out + (size_t)rowg * D_ + lane*4) = o;
}

extern "C" void kernel_launch(void* const* d_in, const int* in_sizes, int n_in,
                              void* d_out, int out_size, void* d_ws, size_t ws_size,
                              hipStream_t stream) {
  const float* x    = (const float*)d_in[0];
  const float* W    = (const float*)d_in[1];
  const float* bias = (const float*)d_in[2];
  float* out = (float*)d_out;
  char* ws = (char*)d_ws;
  unsigned short* xn    = (unsigned short*)(ws);              //  8 MB  bf16 normed x
  unsigned short* Wb    = (unsigned short*)(ws + 8388608);    // 128 KB bf16 W
  float*          norms = (float*)(ws + 8519680);             //  64 KB
  unsigned short* value = (unsigned short*)(ws + 8585216);    //  8 MB  bf16 value
  float*          vsum  = (float*)(ws + 16973824);            //   4 KB
  unsigned short* S     = (unsigned short*)(ws + 16977920);   // 4 x 32 MB ordered-u16 S

  prep_kernel<<<4161, 256, 0, stream>>>(x, W, xn, norms, Wb, vsum);
  compute_kernel<<<4352, 256, 0, stream>>>(xn, norms, Wb, bias, value, vsum, S);
  select_kernel<<<BN_/4, 256, 0, stream>>>(S, value, vsum, out);
}

// Round 11
// 221.715 us; speedup vs baseline: 1.1248x; 1.0905x over previous
//
#include <hip/hip_runtime.h>
#include <hip/hip_bf16.h>
#include <stdint.h>

#define B_ 4
#define N_ 4096
#define D_ 256
#define K_ 64
#define BN_ (B_*N_)

typedef __attribute__((ext_vector_type(8))) short bf16x8;
typedef __attribute__((ext_vector_type(8))) unsigned short u16x8;
typedef __attribute__((ext_vector_type(4))) float f32x4;
typedef __attribute__((address_space(1))) const unsigned int gas_u32;
typedef __attribute__((address_space(3))) unsigned int las_u32;

static __device__ __forceinline__ unsigned short f2bf(float f) {
  union { float f; unsigned u; } x; x.f = f;
  unsigned r = x.u + 0x7fffu + ((x.u >> 16) & 1u);
  return (unsigned short)(r >> 16);
}
static __device__ __forceinline__ float bf2f(unsigned short u) {
  union { unsigned u; float f; } x; x.u = ((unsigned)u) << 16;
  return x.f;
}
static __device__ __forceinline__ f32x4 mfma16(bf16x8 a, bf16x8 b, f32x4 c) {
  return __builtin_amdgcn_mfma_f32_16x16x32_bf16(a, b, c, 0, 0, 0);
}

// ---------------- kernel 1: normalize rows + W->bf16 + vsum zero ----------------
__global__ __launch_bounds__(256) void prep_kernel(
    const float* __restrict__ x, const float* __restrict__ W,
    unsigned short* __restrict__ xn, float* __restrict__ norms,
    unsigned short* __restrict__ Wb, float* __restrict__ vsum) {
  const int bid = blockIdx.x;
  if (bid < 4096) {
    int row = bid * 4 + (threadIdx.x >> 6);
    int lane = threadIdx.x & 63;
    const float4 v = reinterpret_cast<const float4*>(x + (size_t)row * D_)[lane];
    float ss = v.x*v.x + v.y*v.y + v.z*v.z + v.w*v.w;
    #pragma unroll
    for (int off = 32; off > 0; off >>= 1) ss += __shfl_xor(ss, off);
    float nrm = sqrtf(ss);
    float scale = 1.0f / fmaxf(nrm, 1e-12f);
    ushort4 o;
    o.x = f2bf(v.x * scale); o.y = f2bf(v.y * scale);
    o.z = f2bf(v.z * scale); o.w = f2bf(v.w * scale);
    reinterpret_cast<ushort4*>(xn + (size_t)row * D_)[lane] = o;
    if (lane == 0) norms[row] = nrm;
  } else if (bid < 4160) {
    int i = (bid - 4096) * 256 + threadIdx.x;
    float4 v = reinterpret_cast<const float4*>(W)[i];
    ushort4 o; o.x = f2bf(v.x); o.y = f2bf(v.y); o.z = f2bf(v.z); o.w = f2bf(v.w);
    reinterpret_cast<ushort4*>(Wb)[i] = o;
  } else {
    reinterpret_cast<float4*>(vsum)[threadIdx.x] = (float4){0.f, 0.f, 0.f, 0.f};
  }
}

// ---------------- kernel 2: unified 128x128-tile GEMM, 2-phase double-buffer ----
// Catalog T3-minimum: per K-step {STAGE next tile into buf^1 -> ds_read frags
// from buf -> MFMA -> ONE barrier}. Loads issued BEFORE the compute they hide
// under; barrier's vmcnt drain comes ~350cy after issue. LDS 64 KB, 2 blk/CU.
__global__ __launch_bounds__(256, 2) void compute_kernel(
    const unsigned short* __restrict__ xn, const float* __restrict__ norms,
    const unsigned short* __restrict__ Wb, const float* __restrict__ bias,
    unsigned short* __restrict__ value, float* __restrict__ vsum,
    unsigned short* __restrict__ S) {
  __shared__ __attribute__((aligned(16))) unsigned char smem[65536];
  // buf0: A@0, B@16384 ; buf1: A@32768, B@49152

  const int t = threadIdx.x, lane = t & 63, w = t >> 6;
  const int l15 = lane & 15, qv = lane >> 4, rb = qv * 4;
  const int wr = w >> 1, wc = w & 1;
  const int x7 = l15 & 7;

  const int bidx = blockIdx.x;

  const unsigned short* Asrc;
  const unsigned short* Bsrc;
  int rbG, cb, batch = 0;
  const bool vmode = (bidx < 256);
  if (vmode) {
    rbG = (bidx >> 1) * 128;
    cb  = (bidx & 1) * 128;
    Asrc = xn + (size_t)rbG * D_;
    Bsrc = Wb + (size_t)cb * D_;
  } else {
    int g = bidx - 256;
    batch = g >> 10;
    int tl = g & 1023;
    rbG = (tl >> 5) * 128;
    cb  = (tl & 31) * 128;
    Asrc = xn + ((size_t)batch * N_ + rbG) * D_;
    Bsrc = xn + ((size_t)batch * N_ + cb)  * D_;
  }

  auto STAGE = [&](int kk, unsigned char* Ad, unsigned char* Bd) {
    #pragma unroll
    for (int p = 0; p < 4; p++) {
      int q = t + p * 256;                  // 0..1023
      int row = q >> 3, c = q & 7;
      int cg = (c ^ (row & 7)) * 8;         // pre-swizzled source chunk (elems)
      __builtin_amdgcn_global_load_lds(
          (gas_u32*)(Asrc + (size_t)row * D_ + kk * 64 + cg),
          (las_u32*)(Ad + q * 16), 16, 0, 0);
      __builtin_amdgcn_global_load_lds(
          (gas_u32*)(Bsrc + (size_t)row * D_ + kk * 64 + cg),
          (las_u32*)(Bd + q * 16), 16, 0, 0);
    }
  };

  f32x4 acc[4][4];
  #pragma unroll
  for (int i = 0; i < 4; i++)
    #pragma unroll
    for (int j = 0; j < 4; j++) acc[i][j] = (f32x4){0.f,0.f,0.f,0.f};

  STAGE(0, smem, smem + 16384);
  __syncthreads();
  int cur = 0;
  for (int kk = 0; kk < 4; kk++) {
    unsigned char* Ac = smem + cur * 32768;
    unsigned char* Bc = Ac + 16384;
    if (kk < 3) {                           // issue next-tile loads FIRST
      unsigned char* An = smem + (cur ^ 1) * 32768;
      STAGE(kk + 1, An, An + 16384);
    }
    bf16x8 afr[2][4], bfr[2][4];
    #pragma unroll
    for (int ks = 0; ks < 2; ks++) {
      const int cpos = (((ks * 4 + qv) ^ x7) << 4);
      #pragma unroll
      for (int rt = 0; rt < 4; rt++)
        afr[ks][rt] = *(const bf16x8*)(Ac + (wr*64 + rt*16 + l15) * 128 + cpos);
      #pragma unroll
      for (int ct = 0; ct < 4; ct++)
        bfr[ks][ct] = *(const bf16x8*)(Bc + (wc*64 + ct*16 + l15) * 128 + cpos);
    }
    #pragma unroll
    for (int ks = 0; ks < 2; ks++)
      #pragma unroll
      for (int rt = 0; rt < 4; rt++)
        #pragma unroll
        for (int ct = 0; ct < 4; ct++)
          acc[rt][ct] = mfma16(afr[ks][rt], bfr[ks][ct], acc[rt][ct]);
    __syncthreads();                        // one barrier/step: drains stage,
    cur ^= 1;                               // and all reads of buf[cur] done
  }

  // ---- epilogue via swizzled LDS bounce (first 32 KB) ----
  unsigned short* kbuf = (unsigned short*)smem;   // [128][128] u16 = 32 KB
  if (vmode) {
    float nsv[4][4], bsv[4];
    #pragma unroll
    for (int rt = 0; rt < 4; rt++)
      #pragma unroll
      for (int reg = 0; reg < 4; reg++)
        nsv[rt][reg] = norms[rbG + wr*64 + rt*16 + rb + reg];
    #pragma unroll
    for (int ct = 0; ct < 4; ct++)
      bsv[ct] = bias[cb + wc*64 + ct*16 + l15];
    float vpart[4] = {0.f, 0.f, 0.f, 0.f};
    #pragma unroll
    for (int rt = 0; rt < 4; rt++)
      #pragma unroll
      for (int ct = 0; ct < 4; ct++) {
        int col_l = wc*64 + ct*16 + l15;
        #pragma unroll
        for (int reg = 0; reg < 4; reg++) {
          int row_l = wr*64 + rt*16 + rb + reg;
          float v = acc[rt][ct][reg] * nsv[rt][reg] + bsv[ct];
          int pos = (col_l & 7) | ((((col_l >> 3) ^ (row_l & 7))) << 3);
          kbuf[row_l * 128 + pos] = f2bf(v);
          vpart[ct] += v;
        }
      }
    int b2 = rbG >> 12;
    #pragma unroll
    for (int ct = 0; ct < 4; ct++)
      atomicAdd(&vsum[b2*D_ + cb + wc*64 + ct*16 + l15], vpart[ct]);
    __syncthreads();
    #pragma unroll
    for (int p = 0; p < 8; p++) {
      int q = t + p * 256;
      int row = q >> 4, c8 = q & 15;
      u16x8 d = *(const u16x8*)(kbuf + row * 128 + ((c8 ^ (row & 7)) << 3));
      *(u16x8*)(value + (size_t)(rbG + row) * D_ + cb + c8 * 8) = d;
    }
  } else {
    #pragma unroll
    for (int rt = 0; rt < 4; rt++)
      #pragma unroll
      for (int ct = 0; ct < 4; ct++) {
        int col_l = wc*64 + ct*16 + l15;
        #pragma unroll
        for (int reg = 0; reg < 4; reg++) {
          int row_l = wr*64 + rt*16 + rb + reg;
          unsigned short bits = f2bf(acc[rt][ct][reg]);
          unsigned short key = (bits & 0x8000u) ? (unsigned short)(~bits)
                                                : (unsigned short)(bits | 0x8000u);
          int pos = (col_l & 7) | ((((col_l >> 3) ^ (row_l & 7))) << 3);
          kbuf[row_l * 128 + pos] = key;
        }
      }
    __syncthreads();
    unsigned short* Sb = S + ((size_t)batch << 24);
    #pragma unroll
    for (int p = 0; p < 8; p++) {
      int q = t + p * 256;
      int row = q >> 4, c8 = q & 15;
      u16x8 d = *(const u16x8*)(kbuf + row * 128 + ((c8 ^ (row & 7)) << 3));
      *(u16x8*)(Sb + (size_t)(rbG + row) * N_ + cb + c8 * 8) = d;
    }
  }
}

// ---------------- kernel 3: wave-per-row top-64 + sparse softmax @ V ----------
// EXACT round-8 version (proven 86 us): 4 rows/block, one wave per row, zero
// barriers, single wave-private 2048-bin packed histogram.
__global__ __launch_bounds__(256) void select_kernel(
    const unsigned short* __restrict__ S,
    const unsigned short* __restrict__ value,
    const float* __restrict__ vsum,
    float* __restrict__ out) {
  __shared__ unsigned hist[4][1024];      // 16 KB: per-wave packed bins
  __shared__ unsigned pair2[4][64][2];    //  2 KB: (byte-offset, weight bits)
  __shared__ int cnts[4][2];              // nsel, neq per wave

  const int t = threadIdx.x, lane = t & 63, w = t >> 6;
  const int rowg = blockIdx.x * 4 + w;
  const int b = rowg >> 12;
  const int r = rowg & 4095;
  const unsigned short* srow = S + ((size_t)b << 24) + ((size_t)r << 12);

  uint4 kq[8];
  #pragma unroll
  for (int c = 0; c < 8; c++)
    kq[c] = *(const uint4*)(srow + c*512 + lane*8);

  #pragma unroll
  for (int p = 0; p < 4; p++)
    *(uint4*)&hist[w][lane*16 + p*4] = (uint4){0u,0u,0u,0u};
  if (lane == 0) { cnts[w][0] = 0; cnts[w][1] = 0; }

  // pass 1: 2048-bin histogram (bin = key>>5), packed halves
  #pragma unroll
  for (int c = 0; c < 8; c++) {
    unsigned uu[4] = {kq[c].x, kq[c].y, kq[c].z, kq[c].w};
    #pragma unroll
    for (int m = 0; m < 4; m++) {
      unsigned u = uu[m];
      atomicAdd(&hist[w][(u & 0xffffu) >> 6], 1u << (((u >> 5) & 1u) * 16));
      atomicAdd(&hist[w][u >> 22],            1u << (((u >> 21) & 1u) * 16));
    }
  }

  unsigned hw[16];
  #pragma unroll
  for (int p = 0; p < 4; p++)
    *(uint4*)&hw[p*4] = *(const uint4*)&hist[w][lane*16 + p*4];
  unsigned ltot = 0;
  #pragma unroll
  for (int i = 0; i < 16; i++) ltot += (hw[i] & 0xffffu) + (hw[i] >> 16);

  unsigned v = ltot;
  #pragma unroll
  for (int off = 1; off < 64; off <<= 1) {
    unsigned o = __shfl_down(v, off);
    if (lane + off < 64) v += o;
  }
  unsigned above = v - ltot;
  int pk = -1;
  if (v >= 64u && above < 64u) {
    unsigned c = above; int hbl = 0; unsigned cgl = 0;
    #pragma unroll
    for (int j = 31; j >= 0; j--) {
      unsigned cj = (j & 1) ? (hw[j >> 1] >> 16) : (hw[j >> 1] & 0xffffu);
      unsigned cn = c + cj;
      if (cn >= 64u && c < 64u) { hbl = lane*32 + j; cgl = c; }
      c = cn;
    }
    pk = (hbl << 6) | (int)cgl;
  }
  #pragma unroll
  for (int off = 1; off < 64; off <<= 1) pk = max(pk, __shfl_xor(pk, off));
  const unsigned hb = (unsigned)(pk >> 6);
  const unsigned need2 = 64u - (unsigned)(pk & 63);        // >= 1 guaranteed

  // pass 2: 32 bins over low-5 bits within bin hb (16 packed words)
  if (lane < 16) hist[w][lane] = 0;
  #pragma unroll
  for (int c = 0; c < 8; c++) {
    unsigned uu[4] = {kq[c].x, kq[c].y, kq[c].z, kq[c].w};
    #pragma unroll
    for (int m = 0; m < 4; m++) {
      unsigned klo = uu[m] & 0xffffu, khi = uu[m] >> 16;
      if ((klo >> 5) == hb) atomicAdd(&hist[w][(klo & 31u) >> 1], 1u << ((klo & 1u) * 16));
      if ((khi >> 5) == hb) atomicAdd(&hist[w][(khi & 31u) >> 1], 1u << ((khi & 1u) * 16));
    }
  }
  unsigned wv2 = hist[w][lane >> 1];
  unsigned c2 = (lane & 1) ? (wv2 >> 16) : (wv2 & 0xffffu);
  unsigned s2 = c2;
  #pragma unroll
  for (int off = 1; off < 32; off <<= 1) {
    unsigned o = __shfl_down(s2, off);
    if (lane + off < 32) s2 += o;
  }
  unsigned ab2 = s2 - c2;
  int pk2 = -1;
  if (lane < 32 && s2 >= need2 && ab2 < need2) pk2 = (lane << 6) | (int)ab2;
  #pragma unroll
  for (int off = 1; off < 64; off <<= 1) pk2 = max(pk2, __shfl_xor(pk2, off));
  const unsigned tau = (hb << 5) | (unsigned)(pk2 >> 6);
  const int needeq = (int)need2 - (pk2 & 63);              // >= 1 guaranteed

  float zloc = 0.f;
  #pragma unroll
  for (int c = 0; c < 8; c++) {
    int cb0 = c*512 + lane*8;
    unsigned uu[4] = {kq[c].x, kq[c].y, kq[c].z, kq[c].w};
    #pragma unroll
    for (int m = 0; m < 4; m++) {
      #pragma unroll
      for (int h = 0; h < 2; h++) {
        unsigned key = h ? (uu[m] >> 16) : (uu[m] & 0xffffu);
        bool take = key > tau;
        if (!take && key == tau) { int k = atomicAdd(&cnts[w][1], 1); take = (k < needeq); }
        if (take) {
          int slot = atomicAdd(&cnts[w][0], 1);
          unsigned short bits = (key & 0x8000u) ? (unsigned short)(key & 0x7fffu)
                                                : (unsigned short)(~key);
          float e = __expf(bf2f(bits));
          zloc += e;
          pair2[w][slot][0] = (unsigned)(cb0 + m*2 + h) << 9;   // idx * 512 bytes
          pair2[w][slot][1] = __float_as_uint(e - 1.0f);
        }
      }
    }
  }
  #pragma unroll
  for (int off = 32; off > 0; off >>= 1) zloc += __shfl_xor(zloc, off);
  const float invZ = 1.0f / (zloc + (float)(N_ - K_));

  const char* vbb = (const char*)value + ((size_t)b << 21);
  float a0 = 0.f, a1 = 0.f, a2 = 0.f, a3 = 0.f;
  for (int i = 0; i < 64; i++) {
    uint2 pr = *(const uint2*)&pair2[w][i][0];     // broadcast ds_read_b64
    float wt = __uint_as_float(pr.y);
    uint2 vv = *(const uint2*)(vbb + pr.x + lane*8);
    a0 += wt * __uint_as_float(vv.x << 16);
    a1 += wt * __uint_as_float(vv.x & 0xffff0000u);
    a2 += wt * __uint_as_float(vv.y << 16);
    a3 += wt * __uint_as_float(vv.y & 0xffff0000u);
  }
  float4 vs = *(const float4*)(vsum + b*D_ + lane*4);
  float4 o;
  o.x = (a0 + vs.x) * invZ; o.y = (a1 + vs.y) * invZ;
  o.z = (a2 + vs.z) * invZ; o.w = (a3 + vs.w) * invZ;
  *(float4*)(out + (size_t)rowg * D_ + lane*4) = o;
}

extern "C" void kernel_launch(void* const* d_in, const int* in_sizes, int n_in,
                              void* d_out, int out_size, void* d_ws, size_t ws_size,
                              hipStream_t stream) {
  const float* x    = (const float*)d_in[0];
  const float* W    = (const float*)d_in[1];
  const float* bias = (const float*)d_in[2];
  float* out = (float*)d_out;
  char* ws = (char*)d_ws;
  unsigned short* xn    = (unsigned short*)(ws);              //  8 MB  bf16 normed x
  unsigned short* Wb    = (unsigned short*)(ws + 8388608);    // 128 KB bf16 W
  float*          norms = (float*)(ws + 8519680);             //  64 KB
  unsigned short* value = (unsigned short*)(ws + 8585216);    //  8 MB  bf16 value
  float*          vsum  = (float*)(ws + 16973824);            //   4 KB
  unsigned short* S     = (unsigned short*)(ws + 16977920);   // 4 x 32 MB ordered-u16 S

  prep_kernel<<<4161, 256, 0, stream>>>(x, W, xn, norms, Wb, vsum);
  compute_kernel<<<4352, 256, 0, stream>>>(xn, norms, Wb, bias, value, vsum, S);
  select_kernel<<<BN_/4, 256, 0, stream>>>(S, value, vsum, out);
}